// Round 11
// baseline (259.621 us; speedup 1.0000x reference)
//
#include <hip/hip_runtime.h>

#define NN 50000
#define NE 800000
#define D 128
#define SCAN_CH 1024
#define SCAN_NB ((NN + SCAN_CH - 1) / SCAN_CH)  // 49

typedef __attribute__((ext_vector_type(8))) short short8;
typedef __attribute__((ext_vector_type(4))) float f32x4;
typedef unsigned short ushort;
typedef unsigned int uint;
typedef unsigned long long u64;

__device__ inline ushort f2b(float x) {  // f32 -> bf16 RNE
    uint u = __float_as_uint(x);
    return (ushort)((u + 0x7fffu + ((u >> 16) & 1u)) >> 16);
}
__device__ inline float blo(uint u) { return __uint_as_float(u << 16); }
__device__ inline float bhi(uint u) { return __uint_as_float(u & 0xffff0000u); }

// ---------------- fused histogram (one 64-bit atomic/edge, 4 edges/thread)
// ---------------- + W transpose/bf16 folded into the first 32768 threads ----

__global__ __launch_bounds__(256) void k_deg_cnt(const int* __restrict__ dst,
                                                 const float* __restrict__ ew,
                                                 u64* __restrict__ pc,
                                                 int* __restrict__ erank,
                                                 const float* __restrict__ W1,
                                                 const float* __restrict__ W2,
                                                 ushort* __restrict__ wtb1,
                                                 ushort* __restrict__ wtb2, int e4) {
    int i = blockIdx.x * 256 + threadIdx.x;
    if (i < 2 * D * D) {  // weight transpose side-job
        const float* W = (i < D * D) ? W1 : W2;
        ushort* wt = (i < D * D) ? wtb1 : wtb2;
        int idx = (i < D * D) ? i : i - D * D;
        int k = idx >> 7, c = idx & 127;
        wt[c * D + k] = f2b(W[idx]);
    }
    if (i >= e4) return;
    int4 d4 = *(const int4*)&dst[i * 4];
    float4 w4 = *(const float4*)&ew[i * 4];
    int4 r4;
    {
        uint fx = (uint)(w4.x * 16777216.0f + 0.5f);
        r4.x = (int)(atomicAdd(&pc[d4.x], (1ull << 32) | (u64)fx) >> 32);
    }
    {
        uint fx = (uint)(w4.y * 16777216.0f + 0.5f);
        r4.y = (int)(atomicAdd(&pc[d4.y], (1ull << 32) | (u64)fx) >> 32);
    }
    {
        uint fx = (uint)(w4.z * 16777216.0f + 0.5f);
        r4.z = (int)(atomicAdd(&pc[d4.z], (1ull << 32) | (u64)fx) >> 32);
    }
    {
        uint fx = (uint)(w4.w * 16777216.0f + 0.5f);
        r4.w = (int)(atomicAdd(&pc[d4.w], (1ull << 32) | (u64)fx) >> 32);
    }
    *(int4*)&erank[i * 4] = r4;
}

// ---------------- single-pass decoupled-lookback scan + rsd materialization --
// st[b] = (flag<<32)|value; flag: 1=aggregate ready, 2=prefix ready.
// ws poison (0xAAAAAAAA in the flag word) reads as invalid -> no init needed.

__global__ __launch_bounds__(256) void k_scan(const u64* __restrict__ pc,
                                              u64* __restrict__ st,
                                              int* __restrict__ rowptr,
                                              float* __restrict__ rsd, int n, int e) {
    __shared__ int s[256];
    __shared__ int s_excl;
    const int tid = threadIdx.x;
    const int b = blockIdx.x;
    const int base = b * SCAN_CH + tid * 4;
    int c0 = 0, c1 = 0, c2 = 0, c3 = 0;
    const float sc = 1.0f / 16777216.0f;
    if (base + 3 < n) {
        u64 p0 = pc[base + 0], p1 = pc[base + 1], p2 = pc[base + 2], p3 = pc[base + 3];
        c0 = (int)(p0 >> 32); c1 = (int)(p1 >> 32);
        c2 = (int)(p2 >> 32); c3 = (int)(p3 >> 32);
        float4 dv;
        dv.x = rsqrtf(1.0f + (float)(uint)p0 * sc);
        dv.y = rsqrtf(1.0f + (float)(uint)p1 * sc);
        dv.z = rsqrtf(1.0f + (float)(uint)p2 * sc);
        dv.w = rsqrtf(1.0f + (float)(uint)p3 * sc);
        *(float4*)&rsd[base] = dv;
    } else {
        for (int j = 0; j < 4; ++j) {
            if (base + j < n) {
                u64 p = pc[base + j];
                int cj = (int)(p >> 32);
                if (j == 0) c0 = cj; else if (j == 1) c1 = cj; else if (j == 2) c2 = cj; else c3 = cj;
                rsd[base + j] = rsqrtf(1.0f + (float)(uint)p * sc);
            }
        }
    }
    int tsum = c0 + c1 + c2 + c3;
    s[tid] = tsum;
    __syncthreads();
    for (int off = 1; off < 256; off <<= 1) {
        int v = s[tid];
        int add = (tid >= off) ? s[tid - off] : 0;
        __syncthreads();
        s[tid] = v + add;
        __syncthreads();
    }
    int btotal = s[255];
    if (tid == 0) {
        u64 pub = (b == 0) ? (((u64)2 << 32) | (u64)(uint)btotal)
                           : (((u64)1 << 32) | (u64)(uint)btotal);
        __hip_atomic_store(&st[b], pub, __ATOMIC_RELEASE, __HIP_MEMORY_SCOPE_AGENT);
        int excl = 0;
        if (b > 0) {
            int j = b - 1;
            for (;;) {
                u64 v = __hip_atomic_load(&st[j], __ATOMIC_ACQUIRE, __HIP_MEMORY_SCOPE_AGENT);
                uint fl = (uint)(v >> 32);
                if (fl == 2u) { excl += (int)(uint)v; break; }
                if (fl == 1u) { excl += (int)(uint)v; --j; }
                else __builtin_amdgcn_s_sleep(1);
            }
            __hip_atomic_store(&st[b], ((u64)2 << 32) | (u64)(uint)(excl + btotal),
                               __ATOMIC_RELEASE, __HIP_MEMORY_SCOPE_AGENT);
        }
        s_excl = excl;
    }
    __syncthreads();
    int p = s_excl + s[tid] - tsum;
    int p0 = p, p1 = p + c0, p2 = p + c0 + c1, p3 = p + c0 + c1 + c2;
    if (base + 3 < n) {
        *(int4*)&rowptr[base] = make_int4(p0, p1, p2, p3);
    } else {
        if (base + 0 < n) rowptr[base + 0] = p0;
        if (base + 1 < n) rowptr[base + 1] = p1;
        if (base + 2 < n) rowptr[base + 2] = p2;
    }
    if (b == 0 && tid == 0) rowptr[n] = e;
}

// ---------------- scatter: coalesced reads + one random 8B write ----------------

__global__ __launch_bounds__(256) void k_scatter(const int* __restrict__ src,
                                                 const int* __restrict__ dst,
                                                 const float* __restrict__ ew,
                                                 const int* __restrict__ rowptr,
                                                 const int* __restrict__ erank,
                                                 int2* __restrict__ edges, int e) {
    int i = blockIdx.x * 256 + threadIdx.x;
    if (i >= e) return;
    int d = dst[i];
    int pos = rowptr[d] + erank[i];
    int2 ev;
    ev.x = src[i];
    ev.y = __float_as_int(ew[i]);
    edges[pos] = ev;
}

// ---------------- MFMA GEMM: hs(bf16) = rsd-row-scaled (A @ W) ----------------
// BF16IN=false: A is f32 (layer 1 input x); true: A is bf16 (x1b).

template <bool BF16IN>
__global__ __launch_bounds__(256) void k_gemm(const void* __restrict__ Av,
                                              const ushort* __restrict__ wtb,
                                              const float* __restrict__ rsd,
                                              ushort* __restrict__ h, int n) {
    __shared__ ushort bounce[4][16][136];
    const int w = threadIdx.x >> 6, l = threadIdx.x & 63;
    const int r = l & 15, hg = l >> 4;
    const int node = blockIdx.x * 64 + w * 16 + r;
    const bool valid = node < n;

    short8 afr[4];
    if constexpr (BF16IN) {
        const ushort* arow = (const ushort*)Av + (size_t)(valid ? node : 0) * D;
#pragma unroll
        for (int kk = 0; kk < 4; ++kk)
            afr[kk] = *(const short8*)(arow + kk * 32 + hg * 8);
    } else {
        const float* arow = (const float*)Av + (size_t)(valid ? node : 0) * D;
#pragma unroll
        for (int kk = 0; kk < 4; ++kk) {
            float4 p = *(const float4*)(arow + kk * 32 + hg * 8);
            float4 q = *(const float4*)(arow + kk * 32 + hg * 8 + 4);
            short8 t;
            t[0] = (short)f2b(p.x); t[1] = (short)f2b(p.y);
            t[2] = (short)f2b(p.z); t[3] = (short)f2b(p.w);
            t[4] = (short)f2b(q.x); t[5] = (short)f2b(q.y);
            t[6] = (short)f2b(q.z); t[7] = (short)f2b(q.w);
            afr[kk] = t;
        }
    }

    float rs[4];
#pragma unroll
    for (int g = 0; g < 4; ++g) {
        int nd = blockIdx.x * 64 + w * 16 + hg * 4 + g;
        rs[g] = (nd < n) ? rsd[nd] : 1.0f;
    }

#pragma unroll
    for (int ct = 0; ct < 8; ++ct) {
        f32x4 acc = {0.f, 0.f, 0.f, 0.f};
#pragma unroll
        for (int kk = 0; kk < 4; ++kk) {
            short8 b = *(const short8*)(wtb + (size_t)(ct * 16 + r) * D + kk * 32 + hg * 8);
            acc = __builtin_amdgcn_mfma_f32_16x16x32_bf16(afr[kk], b, acc, 0, 0, 0);
        }
#pragma unroll
        for (int g = 0; g < 4; ++g)
            bounce[w][hg * 4 + g][ct * 16 + r] = f2b(acc[g] * rs[g]);
    }
    __syncthreads();

#pragma unroll
    for (int it = 0; it < 4; ++it) {
        int cid = it * 64 + l;
        int nl = cid >> 4;
        int ch = cid & 15;
        int onode = blockIdx.x * 64 + w * 16 + nl;
        if (onode < n) {
            int4 vv = *(const int4*)&bounce[w][nl][ch * 8];
            *(int4*)(h + (size_t)onode * D + ch * 8) = vv;
        }
    }
}

// ---------------- aggregation: one wave per node, 16-deep pipelined gathers ----

#define AGG_BODY                                                               \
    float rv = rsd[v];                                                         \
    uint us = *(const uint*)(hb + (size_t)v * D + f);                          \
    float accx = blo(us);                                                      \
    float accy = bhi(us);                                                      \
    int beg = rowptr[v], end = rowptr[v + 1];                                  \
    for (int base = beg; base < end; base += 64) {                             \
        int idx = base + lane;                                                 \
        int2 ev = (idx < end) ? edges[idx] : make_int2(v, 0);                  \
        int mm = min(64, end - base);                                          \
        for (int sb = 0; sb < 4; ++sb) {                                       \
            if (sb * 16 >= mm) break;                                          \
            uint u[16];                                                        \
            float ws[16];                                                      \
            _Pragma("unroll")                                                  \
            for (int j = 0; j < 16; ++j) {                                     \
                int s = __builtin_amdgcn_readlane(ev.x, sb * 16 + j);          \
                ws[j] = __uint_as_float((uint)__builtin_amdgcn_readlane(ev.y, sb * 16 + j)); \
                u[j] = *(const uint*)(hb + (size_t)s * D + f);                 \
            }                                                                  \
            _Pragma("unroll")                                                  \
            for (int j = 0; j < 16; ++j) {                                     \
                accx += ws[j] * blo(u[j]);                                     \
                accy += ws[j] * bhi(u[j]);                                     \
            }                                                                  \
        }                                                                      \
    }

__global__ __launch_bounds__(256) void k_agg1(const int* __restrict__ rowptr,
                                              const int2* __restrict__ edges,
                                              const float* __restrict__ rsd,
                                              const ushort* __restrict__ hb,
                                              const float* __restrict__ b,
                                              ushort* __restrict__ x1b, int n) {
    int v = (blockIdx.x * 256 + threadIdx.x) >> 6;
    if (v >= n) return;
    int lane = threadIdx.x & 63;
    int f = lane * 2;
    AGG_BODY
    uint ox = (uint)f2b(fmaxf(rv * accx + b[f + 0], 0.0f));
    uint oy = (uint)f2b(fmaxf(rv * accy + b[f + 1], 0.0f));
    *(uint*)&x1b[(size_t)v * D + f] = ox | (oy << 16);
}

__global__ __launch_bounds__(256) void k_agg2(const int* __restrict__ rowptr,
                                              const int2* __restrict__ edges,
                                              const float* __restrict__ rsd,
                                              const ushort* __restrict__ hb,
                                              const ushort* __restrict__ x1b,
                                              const float* __restrict__ b,
                                              float* __restrict__ out, int n) {
    int v = (blockIdx.x * 256 + threadIdx.x) >> 6;
    if (v >= n) return;
    int lane = threadIdx.x & 63;
    int f = lane * 2;
    AGG_BODY
    uint xu = *(const uint*)&x1b[(size_t)v * D + f];
    f32x4 o;
    o[0] = blo(xu);
    o[1] = fmaxf(rv * accx + b[f + 0], 0.0f);
    o[2] = bhi(xu);
    o[3] = fmaxf(rv * accy + b[f + 1], 0.0f);
    __builtin_nontemporal_store(o, (f32x4*)&out[((size_t)v * D + f) * 2]);
}

extern "C" void kernel_launch(void* const* d_in, const int* in_sizes, int n_in,
                              void* d_out, int out_size, void* d_ws, size_t ws_size,
                              hipStream_t stream) {
    const float* x  = (const float*)d_in[0];
    const int*   ei = (const int*)d_in[1];
    const float* ew = (const float*)d_in[2];
    const float* W1 = (const float*)d_in[3];
    const float* b1 = (const float*)d_in[4];
    const float* W2 = (const float*)d_in[5];
    const float* b2 = (const float*)d_in[6];
    float* out = (float*)d_out;

    const int* src = ei;
    const int* dst = ei + NE;

    char* w = (char*)d_ws;
    auto take = [&](size_t bytes) {
        char* p = w;
        w += (bytes + 255) & ~(size_t)255;
        return p;
    };
    u64*    pc        = (u64*)take((size_t)NN * 8);
    float*  rsd       = (float*)take((size_t)NN * 4);
    int*    rowptr    = (int*)take((size_t)(NN + 1) * 4);
    u64*    scanState = (u64*)take((size_t)SCAN_NB * 8);
    int*    erank     = (int*)take((size_t)NE * 4);
    int2*   edges     = (int2*)take((size_t)NE * 8);
    ushort* wtb1      = (ushort*)take((size_t)D * D * 2);
    ushort* wtb2      = (ushort*)take((size_t)D * D * 2);
    ushort* hb        = (ushort*)take((size_t)NN * D * 2);
    ushort* x1b       = (ushort*)take((size_t)NN * D * 2);

    const int nBlkE   = (NE + 255) / 256;
    const int nBlkE4  = (NE / 4 + 255) / 256;
    const int nBlkG   = (NN + 63) / 64;
    const int nBlkAgg = (NN * 64 + 255) / 256;

    // CSR build
    (void)hipMemsetAsync(pc, 0, (size_t)NN * 8, stream);
    k_deg_cnt<<<nBlkE4, 256, 0, stream>>>(dst, ew, pc, erank, W1, W2, wtb1, wtb2, NE / 4);
    k_scan<<<SCAN_NB, 256, 0, stream>>>(pc, scanState, rowptr, rsd, NN, NE);
    k_scatter<<<nBlkE, 256, 0, stream>>>(src, dst, ew, rowptr, erank, edges, NE);

    // layer 1
    k_gemm<false><<<nBlkG, 256, 0, stream>>>(x, wtb1, rsd, hb, NN);
    k_agg1<<<nBlkAgg, 256, 0, stream>>>(rowptr, edges, rsd, hb, b1, x1b, NN);

    // layer 2
    k_gemm<true><<<nBlkG, 256, 0, stream>>>(x1b, wtb2, rsd, hb, NN);
    k_agg2<<<nBlkAgg, 256, 0, stream>>>(rowptr, edges, rsd, hb, x1b, b2, out, NN);
}